// Round 2
// baseline (1155.162 us; speedup 1.0000x reference)
//
#include <hip/hip_runtime.h>

#define N_NODES 100000
#define N_EDGES 1250000
#define D 64

#define SCAN_TPB 256
#define SCAN_ELEMS 1024
#define SCAN_NB ((N_NODES + SCAN_ELEMS - 1) / SCAN_ELEMS)   // 98

// ---- bf16 helpers (finite values only) ----
__device__ inline unsigned short f2bf(float f) {
    unsigned int u = __float_as_uint(f);
    unsigned int r = (u + 0x7fffu + ((u >> 16) & 1u)) >> 16;
    return (unsigned short)r;
}
__device__ inline float bf2f(unsigned short b) {
    return __uint_as_float(((unsigned int)b) << 16);
}

__device__ inline float load_val(const float* p) { return *p; }
__device__ inline float load_val(const unsigned short* p) { return bf2f(*p); }

// ---------------- zero hist ----------------
__global__ void zero_int_kernel(int* __restrict__ p, int n) {
    int i = blockIdx.x * blockDim.x + threadIdx.x;
    if (i < n) p[i] = 0;
}

// ---------------- degree histogram ----------------
__global__ __launch_bounds__(256)
void hist_kernel(const int* __restrict__ dst, int* __restrict__ hist) {
    int e = blockIdx.x * 256 + threadIdx.x;
    if (e < N_EDGES) atomicAdd(&hist[dst[e]], 1);
}

// ---------------- scan step 1: per-block reduce ----------------
__global__ __launch_bounds__(SCAN_TPB)
void scan_reduce_kernel(const int* __restrict__ hist, int* __restrict__ partials) {
    __shared__ int sdata[SCAN_TPB];
    int t = threadIdx.x;
    int base = blockIdx.x * SCAN_ELEMS + t * 4;
    int s = 0;
#pragma unroll
    for (int k = 0; k < 4; ++k) {
        int i = base + k;
        if (i < N_NODES) s += hist[i];
    }
    sdata[t] = s;
    __syncthreads();
    for (int off = SCAN_TPB / 2; off > 0; off >>= 1) {
        if (t < off) sdata[t] += sdata[t + off];
        __syncthreads();
    }
    if (t == 0) partials[blockIdx.x] = sdata[0];
}

// ---------------- scan step 2: exclusive scan of partials (1 block) ----------------
__global__ __launch_bounds__(128)
void scan_partials_kernel(int* __restrict__ partials) {
    __shared__ int s[128];
    int t = threadIdx.x;
    int v = (t < SCAN_NB) ? partials[t] : 0;
    s[t] = v;
    __syncthreads();
    for (int off = 1; off < 128; off <<= 1) {
        int x = (t >= off) ? s[t - off] : 0;
        __syncthreads();
        s[t] += x;
        __syncthreads();
    }
    if (t < SCAN_NB) partials[t] = (t == 0) ? 0 : s[t - 1];
}

// ---------------- scan step 3: write exclusive prefix -> cursor ----------------
__global__ __launch_bounds__(SCAN_TPB)
void scan_write_kernel(const int* __restrict__ hist, const int* __restrict__ partials,
                       int* __restrict__ cursor) {
    __shared__ int sdata[SCAN_TPB];
    int t = threadIdx.x;
    int base = blockIdx.x * SCAN_ELEMS + t * 4;
    int h[4];
    int tot = 0;
#pragma unroll
    for (int k = 0; k < 4; ++k) {
        int i = base + k;
        h[k] = (i < N_NODES) ? hist[i] : 0;
        tot += h[k];
    }
    sdata[t] = tot;
    __syncthreads();
    for (int off = 1; off < SCAN_TPB; off <<= 1) {
        int x = (t >= off) ? sdata[t - off] : 0;
        __syncthreads();
        sdata[t] += x;
        __syncthreads();
    }
    int run = partials[blockIdx.x] + sdata[t] - tot;   // exclusive thread prefix
#pragma unroll
    for (int k = 0; k < 4; ++k) {
        int i = base + k;
        if (i < N_NODES) { cursor[i] = run; run += h[k]; }
    }
}

// ---------------- bucket: counting-sort srcs by dst ----------------
// after this, cursor[n] == row_end[n]; row_start[n] = cursor[n] - hist[n]
__global__ __launch_bounds__(256)
void bucket_kernel(const int* __restrict__ src, const int* __restrict__ dst,
                   int* __restrict__ cursor, int* __restrict__ sorted_src) {
    int e = blockIdx.x * 256 + threadIdx.x;
    if (e < N_EDGES) {
        int d = dst[e];
        int pos = atomicAdd(&cursor[d], 1);
        sorted_src[pos] = src[e];
    }
}

// ---------------- fused layer: gather-mean + (mean@Wl + b + x@Wr) ----------------
template <typename TIN, typename TOUT>
__global__ __launch_bounds__(256, 2)
void fused_layer_kernel(const TIN* __restrict__ xin,
                        const int* __restrict__ cursor_end,
                        const int* __restrict__ deg,
                        const int* __restrict__ sorted_src,
                        const float* __restrict__ Wl,
                        const float* __restrict__ bl,
                        const float* __restrict__ Wr,
                        TOUT* __restrict__ out,
                        int relu) {
    __shared__ float sM[64][68];
    __shared__ float sX[64][68];
    __shared__ float sWl[64][64];
    __shared__ float sWr[64][64];

    const int tid = threadIdx.x;
    const int row0 = blockIdx.x * 64;

    // stage weights
    for (int i = tid; i < 1024; i += 256) {
        ((float4*)&sWl[0][0])[i] = ((const float4*)Wl)[i];
        ((float4*)&sWr[0][0])[i] = ((const float4*)Wr)[i];
    }

    // gather phase: wave per row, lane = feature
    const int wave = tid >> 6;
    const int lane = tid & 63;
    for (int r = wave; r < 64; r += 4) {
        int n = row0 + r;
        float acc = 0.f, xv = 0.f;
        int dg = 0;
        if (n < N_NODES) {
            dg = deg[n];
            int st = cursor_end[n] - dg;
            for (int i = 0; i < dg; ++i) {
                int s = sorted_src[st + i];
                acc += load_val(xin + (size_t)s * D + lane);
            }
            xv = load_val(xin + (size_t)n * D + lane);
        }
        sM[r][lane] = acc / (float)(dg > 0 ? dg : 1);
        sX[r][lane] = xv;
    }
    __syncthreads();

    const int tx = tid & 15, ty = tid >> 4;
    const int j0 = tx * 4;
    const int i0 = ty * 4;

    float acc[4][4];
    float4 b4 = *(const float4*)&bl[j0];
#pragma unroll
    for (int i = 0; i < 4; ++i) {
        acc[i][0] = b4.x; acc[i][1] = b4.y; acc[i][2] = b4.z; acc[i][3] = b4.w;
    }

    for (int k = 0; k < 64; k += 4) {
        float4 wl[4], wr[4];
#pragma unroll
        for (int kk = 0; kk < 4; ++kk) {
            wl[kk] = *(const float4*)&sWl[k + kk][j0];
            wr[kk] = *(const float4*)&sWr[k + kk][j0];
        }
#pragma unroll
        for (int i = 0; i < 4; ++i) {
            float4 m  = *(const float4*)&sM[i0 + i][k];
            float4 xv = *(const float4*)&sX[i0 + i][k];
            float mk[4] = {m.x, m.y, m.z, m.w};
            float xk[4] = {xv.x, xv.y, xv.z, xv.w};
#pragma unroll
            for (int kk = 0; kk < 4; ++kk) {
                acc[i][0] += mk[kk] * wl[kk].x + xk[kk] * wr[kk].x;
                acc[i][1] += mk[kk] * wl[kk].y + xk[kk] * wr[kk].y;
                acc[i][2] += mk[kk] * wl[kk].z + xk[kk] * wr[kk].z;
                acc[i][3] += mk[kk] * wl[kk].w + xk[kk] * wr[kk].w;
            }
        }
    }

#pragma unroll
    for (int i = 0; i < 4; ++i) {
        int n = row0 + i0 + i;
        if (n < N_NODES) {
            float o[4];
#pragma unroll
            for (int j = 0; j < 4; ++j)
                o[j] = relu ? fmaxf(acc[i][j], 0.f) : acc[i][j];
            if constexpr (__hip_internal::is_same<TOUT, unsigned short>::value) {
                ushort4 u;
                u.x = f2bf(o[0]); u.y = f2bf(o[1]); u.z = f2bf(o[2]); u.w = f2bf(o[3]);
                *(ushort4*)&out[(size_t)n * D + j0] = u;
            } else {
                float4 f;
                f.x = o[0]; f.y = o[1]; f.z = o[2]; f.w = o[3];
                *(float4*)&out[(size_t)n * D + j0] = f;
            }
        }
    }
}

extern "C" void kernel_launch(void* const* d_in, const int* in_sizes, int n_in,
                              void* d_out, int out_size, void* d_ws, size_t ws_size,
                              hipStream_t stream) {
    const float* x   = (const float*)d_in[0];
    const int*   ei  = (const int*)d_in[1];
    const float* Wl1 = (const float*)d_in[2];
    const float* b1  = (const float*)d_in[3];
    const float* Wr1 = (const float*)d_in[4];
    const float* Wl2 = (const float*)d_in[5];
    const float* b2  = (const float*)d_in[6];
    const float* Wr2 = (const float*)d_in[7];

    const int* src = ei;
    const int* dst = ei + N_EDGES;

    // ws layout (ints): hist[100000] | cursor[100000] | partials[128] | sorted_src[1250000] | h_bf16
    int* hist       = (int*)d_ws;
    int* cursor     = hist + N_NODES;
    int* partials   = cursor + N_NODES;
    int* sorted_src = partials + 128;
    unsigned short* h = (unsigned short*)(sorted_src + N_EDGES);   // [N, D] bf16
    float* out = (float*)d_out;

    const int edge_blocks = (N_EDGES + 255) / 256;
    const int node_blocks = (N_NODES + 255) / 256;
    const int dense_blocks = (N_NODES + 63) / 64;

    // build CSR (dst-sorted srcs)
    zero_int_kernel<<<node_blocks, 256, 0, stream>>>(hist, N_NODES);
    hist_kernel<<<edge_blocks, 256, 0, stream>>>(dst, hist);
    scan_reduce_kernel<<<SCAN_NB, SCAN_TPB, 0, stream>>>(hist, partials);
    scan_partials_kernel<<<1, 128, 0, stream>>>(partials);
    scan_write_kernel<<<SCAN_NB, SCAN_TPB, 0, stream>>>(hist, partials, cursor);
    bucket_kernel<<<edge_blocks, 256, 0, stream>>>(src, dst, cursor, sorted_src);

    // layer 1: x (fp32) -> h (bf16, ws)
    fused_layer_kernel<float, unsigned short><<<dense_blocks, 256, 0, stream>>>(
        x, cursor, hist, sorted_src, Wl1, b1, Wr1, h, /*relu=*/1);
    // layer 2: h (bf16) -> out (fp32, d_out)
    fused_layer_kernel<unsigned short, float><<<dense_blocks, 256, 0, stream>>>(
        h, cursor, hist, sorted_src, Wl2, b2, Wr2, out, /*relu=*/0);
}

// Round 3
// 492.702 us; speedup vs baseline: 2.3445x; 2.3445x over previous
//
#include <hip/hip_runtime.h>

#define N_NODES 100000
#define N_EDGES 1250000
#define D 64

#define SCAN_TPB 256
#define SCAN_ELEMS 1024
#define SCAN_NB ((N_NODES + SCAN_ELEMS - 1) / SCAN_ELEMS)   // 98

// ---- bf16 helpers (finite values only) ----
__device__ inline unsigned short f2bf(float f) {
    unsigned int u = __float_as_uint(f);
    unsigned int r = (u + 0x7fffu + ((u >> 16) & 1u)) >> 16;
    return (unsigned short)r;
}
__device__ inline float bf2f(unsigned short b) {
    return __uint_as_float(((unsigned int)b) << 16);
}

__device__ inline float load_val(const float* p) { return *p; }
__device__ inline float load_val(const unsigned short* p) { return bf2f(*p); }

// ---------------- zero hist ----------------
__global__ void zero_int_kernel(int* __restrict__ p, int n) {
    int i = blockIdx.x * blockDim.x + threadIdx.x;
    if (i < n) p[i] = 0;
}

// ---------------- degree histogram ----------------
__global__ __launch_bounds__(256)
void hist_kernel(const int* __restrict__ dst, int* __restrict__ hist) {
    int e = blockIdx.x * 256 + threadIdx.x;
    if (e < N_EDGES) atomicAdd(&hist[dst[e]], 1);
}

// ---------------- scan step 1: per-block reduce ----------------
__global__ __launch_bounds__(SCAN_TPB)
void scan_reduce_kernel(const int* __restrict__ hist, int* __restrict__ partials) {
    __shared__ int sdata[SCAN_TPB];
    int t = threadIdx.x;
    int base = blockIdx.x * SCAN_ELEMS + t * 4;
    int s = 0;
#pragma unroll
    for (int k = 0; k < 4; ++k) {
        int i = base + k;
        if (i < N_NODES) s += hist[i];
    }
    sdata[t] = s;
    __syncthreads();
    for (int off = SCAN_TPB / 2; off > 0; off >>= 1) {
        if (t < off) sdata[t] += sdata[t + off];
        __syncthreads();
    }
    if (t == 0) partials[blockIdx.x] = sdata[0];
}

// ---------------- scan step 2: exclusive scan of partials (1 block) ----------------
__global__ __launch_bounds__(128)
void scan_partials_kernel(int* __restrict__ partials) {
    __shared__ int s[128];
    int t = threadIdx.x;
    int v = (t < SCAN_NB) ? partials[t] : 0;
    s[t] = v;
    __syncthreads();
    for (int off = 1; off < 128; off <<= 1) {
        int x = (t >= off) ? s[t - off] : 0;
        __syncthreads();
        s[t] += x;
        __syncthreads();
    }
    if (t < SCAN_NB) partials[t] = (t == 0) ? 0 : s[t - 1];
}

// ---------------- scan step 3: write exclusive prefix -> cursor ----------------
__global__ __launch_bounds__(SCAN_TPB)
void scan_write_kernel(const int* __restrict__ hist, const int* __restrict__ partials,
                       int* __restrict__ cursor) {
    __shared__ int sdata[SCAN_TPB];
    int t = threadIdx.x;
    int base = blockIdx.x * SCAN_ELEMS + t * 4;
    int h[4];
    int tot = 0;
#pragma unroll
    for (int k = 0; k < 4; ++k) {
        int i = base + k;
        h[k] = (i < N_NODES) ? hist[i] : 0;
        tot += h[k];
    }
    sdata[t] = tot;
    __syncthreads();
    for (int off = 1; off < SCAN_TPB; off <<= 1) {
        int x = (t >= off) ? sdata[t - off] : 0;
        __syncthreads();
        sdata[t] += x;
        __syncthreads();
    }
    int run = partials[blockIdx.x] + sdata[t] - tot;   // exclusive thread prefix
#pragma unroll
    for (int k = 0; k < 4; ++k) {
        int i = base + k;
        if (i < N_NODES) { cursor[i] = run; run += h[k]; }
    }
}

// ---------------- bucket: counting-sort srcs by dst ----------------
__global__ __launch_bounds__(256)
void bucket_kernel(const int* __restrict__ src, const int* __restrict__ dst,
                   int* __restrict__ cursor, int* __restrict__ sorted_src) {
    int e = blockIdx.x * 256 + threadIdx.x;
    if (e < N_EDGES) {
        int d = dst[e];
        int pos = atomicAdd(&cursor[d], 1);
        sorted_src[pos] = src[e];
    }
}

// ---------------- fused layer: gather-mean + (mean@Wl + b + x@Wr) ----------------
// 32-row tile, 50 KB LDS -> 3 blocks/CU. Gather: batched index load + 8-deep MLP.
template <typename TIN, typename TOUT>
__global__ __launch_bounds__(256, 3)
void fused_layer_kernel(const TIN* __restrict__ xin,
                        const int* __restrict__ cursor_end,
                        const int* __restrict__ deg,
                        const int* __restrict__ sorted_src,
                        const float* __restrict__ Wl,
                        const float* __restrict__ bl,
                        const float* __restrict__ Wr,
                        TOUT* __restrict__ out,
                        int relu) {
    __shared__ float sM[32][68];
    __shared__ float sX[32][68];
    __shared__ float sWl[64][64];
    __shared__ float sWr[64][64];

    const int tid = threadIdx.x;
    const int row0 = blockIdx.x * 32;

    // stage weights (1024 float4 each, 4 iters/thread)
    for (int i = tid; i < 1024; i += 256) {
        ((float4*)&sWl[0][0])[i] = ((const float4*)Wl)[i];
        ((float4*)&sWr[0][0])[i] = ((const float4*)Wr)[i];
    }

    // gather phase: wave per row, lane = feature, 8 rows per wave
    const int wave = tid >> 6;
    const int lane = tid & 63;
    for (int r = wave; r < 32; r += 4) {
        int n = row0 + r;
        float acc = 0.f, xv = 0.f;
        int dg = 0;
        if (n < N_NODES) {
            dg = deg[n];
            int st = cursor_end[n] - dg;
            xv = load_val(xin + (size_t)n * D + lane);
            for (int base = 0; base < dg; base += 64) {
                int m = dg - base; if (m > 64) m = 64;
                // one coalesced load fetches up to 64 edge indices
                int idx = 0;
                if (lane < m) idx = sorted_src[st + base + lane];
                float a0 = 0.f, a1 = 0.f, a2 = 0.f, a3 = 0.f;
                float a4 = 0.f, a5 = 0.f, a6 = 0.f, a7 = 0.f;
                int j = 0;
                for (; j + 8 <= m; j += 8) {
                    int s0 = __builtin_amdgcn_readlane(idx, j + 0);
                    int s1 = __builtin_amdgcn_readlane(idx, j + 1);
                    int s2 = __builtin_amdgcn_readlane(idx, j + 2);
                    int s3 = __builtin_amdgcn_readlane(idx, j + 3);
                    int s4 = __builtin_amdgcn_readlane(idx, j + 4);
                    int s5 = __builtin_amdgcn_readlane(idx, j + 5);
                    int s6 = __builtin_amdgcn_readlane(idx, j + 6);
                    int s7 = __builtin_amdgcn_readlane(idx, j + 7);
                    a0 += load_val(xin + (size_t)s0 * D + lane);
                    a1 += load_val(xin + (size_t)s1 * D + lane);
                    a2 += load_val(xin + (size_t)s2 * D + lane);
                    a3 += load_val(xin + (size_t)s3 * D + lane);
                    a4 += load_val(xin + (size_t)s4 * D + lane);
                    a5 += load_val(xin + (size_t)s5 * D + lane);
                    a6 += load_val(xin + (size_t)s6 * D + lane);
                    a7 += load_val(xin + (size_t)s7 * D + lane);
                }
                for (; j < m; ++j) {
                    int s = __builtin_amdgcn_readlane(idx, j);
                    a0 += load_val(xin + (size_t)s * D + lane);
                }
                acc += ((a0 + a1) + (a2 + a3)) + ((a4 + a5) + (a6 + a7));
            }
        }
        sM[r][lane] = acc / (float)(dg > 0 ? dg : 1);
        sX[r][lane] = xv;
    }
    __syncthreads();

    // GEMM phase: thread = 2 rows x 4 cols
    const int tx = tid & 15, ty = tid >> 4;   // ty 0..15
    const int j0 = tx * 4;
    const int i0 = ty * 2;

    float acc[2][4];
    float4 b4 = *(const float4*)&bl[j0];
#pragma unroll
    for (int i = 0; i < 2; ++i) {
        acc[i][0] = b4.x; acc[i][1] = b4.y; acc[i][2] = b4.z; acc[i][3] = b4.w;
    }

    for (int k = 0; k < 64; k += 4) {
        float4 wl[4], wr[4];
#pragma unroll
        for (int kk = 0; kk < 4; ++kk) {
            wl[kk] = *(const float4*)&sWl[k + kk][j0];
            wr[kk] = *(const float4*)&sWr[k + kk][j0];
        }
#pragma unroll
        for (int i = 0; i < 2; ++i) {
            float4 m  = *(const float4*)&sM[i0 + i][k];
            float4 xv = *(const float4*)&sX[i0 + i][k];
            float mk[4] = {m.x, m.y, m.z, m.w};
            float xk[4] = {xv.x, xv.y, xv.z, xv.w};
#pragma unroll
            for (int kk = 0; kk < 4; ++kk) {
                acc[i][0] += mk[kk] * wl[kk].x + xk[kk] * wr[kk].x;
                acc[i][1] += mk[kk] * wl[kk].y + xk[kk] * wr[kk].y;
                acc[i][2] += mk[kk] * wl[kk].z + xk[kk] * wr[kk].z;
                acc[i][3] += mk[kk] * wl[kk].w + xk[kk] * wr[kk].w;
            }
        }
    }

#pragma unroll
    for (int i = 0; i < 2; ++i) {
        int n = row0 + i0 + i;
        if (n < N_NODES) {
            float o[4];
#pragma unroll
            for (int j = 0; j < 4; ++j)
                o[j] = relu ? fmaxf(acc[i][j], 0.f) : acc[i][j];
            if constexpr (__hip_internal::is_same<TOUT, unsigned short>::value) {
                ushort4 u;
                u.x = f2bf(o[0]); u.y = f2bf(o[1]); u.z = f2bf(o[2]); u.w = f2bf(o[3]);
                *(ushort4*)&out[(size_t)n * D + j0] = u;
            } else {
                float4 f;
                f.x = o[0]; f.y = o[1]; f.z = o[2]; f.w = o[3];
                *(float4*)&out[(size_t)n * D + j0] = f;
            }
        }
    }
}

extern "C" void kernel_launch(void* const* d_in, const int* in_sizes, int n_in,
                              void* d_out, int out_size, void* d_ws, size_t ws_size,
                              hipStream_t stream) {
    const float* x   = (const float*)d_in[0];
    const int*   ei  = (const int*)d_in[1];
    const float* Wl1 = (const float*)d_in[2];
    const float* b1  = (const float*)d_in[3];
    const float* Wr1 = (const float*)d_in[4];
    const float* Wl2 = (const float*)d_in[5];
    const float* b2  = (const float*)d_in[6];
    const float* Wr2 = (const float*)d_in[7];

    const int* src = ei;
    const int* dst = ei + N_EDGES;

    // ws layout (ints): hist[100000] | cursor[100000] | partials[128] | sorted_src[1250000] | h_bf16
    int* hist       = (int*)d_ws;
    int* cursor     = hist + N_NODES;
    int* partials   = cursor + N_NODES;
    int* sorted_src = partials + 128;
    unsigned short* h = (unsigned short*)(sorted_src + N_EDGES);   // [N, D] bf16
    float* out = (float*)d_out;

    const int edge_blocks = (N_EDGES + 255) / 256;
    const int node_blocks = (N_NODES + 255) / 256;
    const int dense_blocks = (N_NODES + 31) / 32;

    // build CSR (dst-sorted srcs)
    zero_int_kernel<<<node_blocks, 256, 0, stream>>>(hist, N_NODES);
    hist_kernel<<<edge_blocks, 256, 0, stream>>>(dst, hist);
    scan_reduce_kernel<<<SCAN_NB, SCAN_TPB, 0, stream>>>(hist, partials);
    scan_partials_kernel<<<1, 128, 0, stream>>>(partials);
    scan_write_kernel<<<SCAN_NB, SCAN_TPB, 0, stream>>>(hist, partials, cursor);
    bucket_kernel<<<edge_blocks, 256, 0, stream>>>(src, dst, cursor, sorted_src);

    // layer 1: x (fp32) -> h (bf16, ws)
    fused_layer_kernel<float, unsigned short><<<dense_blocks, 256, 0, stream>>>(
        x, cursor, hist, sorted_src, Wl1, b1, Wr1, h, /*relu=*/1);
    // layer 2: h (bf16) -> out (fp32, d_out)
    fused_layer_kernel<unsigned short, float><<<dense_blocks, 256, 0, stream>>>(
        h, cursor, hist, sorted_src, Wl2, b2, Wr2, out, /*relu=*/0);
}

// Round 4
// 428.504 us; speedup vs baseline: 2.6958x; 1.1498x over previous
//
#include <hip/hip_runtime.h>

#define N_NODES 100000
#define N_EDGES 1250000
#define D 64

#define SCAN_TPB 256
#define SCAN_ELEMS 1024
#define SCAN_NB ((N_NODES + SCAN_ELEMS - 1) / SCAN_ELEMS)   // 98

// ---- bf16 helpers (finite values only) ----
__device__ inline unsigned short f2bf(float f) {
    unsigned int u = __float_as_uint(f);
    unsigned int r = (u + 0x7fffu + ((u >> 16) & 1u)) >> 16;
    return (unsigned short)r;
}
__device__ inline float bf2f(unsigned short b) {
    return __uint_as_float(((unsigned int)b) << 16);
}

// ---------------- x fp32 -> bf16 ----------------
__global__ __launch_bounds__(256)
void convert_kernel(const float4* __restrict__ xin, ushort4* __restrict__ xb, int n4) {
    int i = blockIdx.x * 256 + threadIdx.x;
    if (i < n4) {
        float4 v = xin[i];
        ushort4 u;
        u.x = f2bf(v.x); u.y = f2bf(v.y); u.z = f2bf(v.z); u.w = f2bf(v.w);
        xb[i] = u;
    }
}

// ---------------- zero hist ----------------
__global__ void zero_int_kernel(int* __restrict__ p, int n) {
    int i = blockIdx.x * blockDim.x + threadIdx.x;
    if (i < n) p[i] = 0;
}

// ---------------- degree histogram ----------------
__global__ __launch_bounds__(256)
void hist_kernel(const int* __restrict__ dst, int* __restrict__ hist) {
    int e = blockIdx.x * 256 + threadIdx.x;
    if (e < N_EDGES) atomicAdd(&hist[dst[e]], 1);
}

// ---------------- scan step 1: per-block reduce ----------------
__global__ __launch_bounds__(SCAN_TPB)
void scan_reduce_kernel(const int* __restrict__ hist, int* __restrict__ partials) {
    __shared__ int sdata[SCAN_TPB];
    int t = threadIdx.x;
    int base = blockIdx.x * SCAN_ELEMS + t * 4;
    int s = 0;
#pragma unroll
    for (int k = 0; k < 4; ++k) {
        int i = base + k;
        if (i < N_NODES) s += hist[i];
    }
    sdata[t] = s;
    __syncthreads();
    for (int off = SCAN_TPB / 2; off > 0; off >>= 1) {
        if (t < off) sdata[t] += sdata[t + off];
        __syncthreads();
    }
    if (t == 0) partials[blockIdx.x] = sdata[0];
}

// ---------------- scan step 2: exclusive scan of partials (1 block) ----------------
__global__ __launch_bounds__(128)
void scan_partials_kernel(int* __restrict__ partials) {
    __shared__ int s[128];
    int t = threadIdx.x;
    int v = (t < SCAN_NB) ? partials[t] : 0;
    s[t] = v;
    __syncthreads();
    for (int off = 1; off < 128; off <<= 1) {
        int x = (t >= off) ? s[t - off] : 0;
        __syncthreads();
        s[t] += x;
        __syncthreads();
    }
    if (t < SCAN_NB) partials[t] = (t == 0) ? 0 : s[t - 1];
}

// ---------------- scan step 3: write exclusive prefix -> cursor ----------------
__global__ __launch_bounds__(SCAN_TPB)
void scan_write_kernel(const int* __restrict__ hist, const int* __restrict__ partials,
                       int* __restrict__ cursor) {
    __shared__ int sdata[SCAN_TPB];
    int t = threadIdx.x;
    int base = blockIdx.x * SCAN_ELEMS + t * 4;
    int h[4];
    int tot = 0;
#pragma unroll
    for (int k = 0; k < 4; ++k) {
        int i = base + k;
        h[k] = (i < N_NODES) ? hist[i] : 0;
        tot += h[k];
    }
    sdata[t] = tot;
    __syncthreads();
    for (int off = 1; off < SCAN_TPB; off <<= 1) {
        int x = (t >= off) ? sdata[t - off] : 0;
        __syncthreads();
        sdata[t] += x;
        __syncthreads();
    }
    int run = partials[blockIdx.x] + sdata[t] - tot;   // exclusive thread prefix
#pragma unroll
    for (int k = 0; k < 4; ++k) {
        int i = base + k;
        if (i < N_NODES) { cursor[i] = run; run += h[k]; }
    }
}

// ---------------- bucket: counting-sort srcs by dst ----------------
__global__ __launch_bounds__(256)
void bucket_kernel(const int* __restrict__ src, const int* __restrict__ dst,
                   int* __restrict__ cursor, int* __restrict__ sorted_src) {
    int e = blockIdx.x * 256 + threadIdx.x;
    if (e < N_EDGES) {
        int d = dst[e];
        int pos = atomicAdd(&cursor[d], 1);
        sorted_src[pos] = src[e];
    }
}

// ---------------- fused layer: gather-mean + (mean@Wl + b + x@Wr) ----------------
// bf16 input. 32-row tile, 17.4 KB LDS (weights read from global -> L1/L2),
// 6 blocks/CU (24 waves) for latency hiding in the gather.
template <typename TOUT>
__global__ __launch_bounds__(256, 6)
void fused_layer_kernel(const unsigned short* __restrict__ xin,   // bf16 [N,D]
                        const int* __restrict__ cursor_end,
                        const int* __restrict__ deg,
                        const int* __restrict__ sorted_src,
                        const float* __restrict__ Wl,
                        const float* __restrict__ bl,
                        const float* __restrict__ Wr,
                        TOUT* __restrict__ out,
                        int relu) {
    __shared__ float sM[32][68];
    __shared__ float sX[32][68];

    const int tid = threadIdx.x;
    const int row0 = blockIdx.x * 32;

    // gather phase: wave per row, lane = feature, 8 rows per wave
    const int wave = tid >> 6;
    const int lane = tid & 63;
    for (int r = wave; r < 32; r += 4) {
        int n = row0 + r;
        float acc = 0.f, xv = 0.f;
        int dg = 0;
        if (n < N_NODES) {
            dg = deg[n];
            int st = cursor_end[n] - dg;
            xv = bf2f(xin[(size_t)n * D + lane]);
            for (int base = 0; base < dg; base += 64) {
                int m = dg - base; if (m > 64) m = 64;
                // one coalesced load fetches up to 64 edge indices
                int idx = 0;
                if (lane < m) idx = sorted_src[st + base + lane];
                float a0 = 0.f, a1 = 0.f, a2 = 0.f, a3 = 0.f;
                float a4 = 0.f, a5 = 0.f, a6 = 0.f, a7 = 0.f;
                int j = 0;
                for (; j + 8 <= m; j += 8) {
                    int s0 = __builtin_amdgcn_readlane(idx, j + 0);
                    int s1 = __builtin_amdgcn_readlane(idx, j + 1);
                    int s2 = __builtin_amdgcn_readlane(idx, j + 2);
                    int s3 = __builtin_amdgcn_readlane(idx, j + 3);
                    int s4 = __builtin_amdgcn_readlane(idx, j + 4);
                    int s5 = __builtin_amdgcn_readlane(idx, j + 5);
                    int s6 = __builtin_amdgcn_readlane(idx, j + 6);
                    int s7 = __builtin_amdgcn_readlane(idx, j + 7);
                    a0 += bf2f(xin[(size_t)s0 * D + lane]);
                    a1 += bf2f(xin[(size_t)s1 * D + lane]);
                    a2 += bf2f(xin[(size_t)s2 * D + lane]);
                    a3 += bf2f(xin[(size_t)s3 * D + lane]);
                    a4 += bf2f(xin[(size_t)s4 * D + lane]);
                    a5 += bf2f(xin[(size_t)s5 * D + lane]);
                    a6 += bf2f(xin[(size_t)s6 * D + lane]);
                    a7 += bf2f(xin[(size_t)s7 * D + lane]);
                }
                for (; j < m; ++j) {
                    int s = __builtin_amdgcn_readlane(idx, j);
                    a0 += bf2f(xin[(size_t)s * D + lane]);
                }
                acc += ((a0 + a1) + (a2 + a3)) + ((a4 + a5) + (a6 + a7));
            }
        }
        sM[r][lane] = acc / (float)(dg > 0 ? dg : 1);
        sX[r][lane] = xv;
    }
    __syncthreads();

    // GEMM phase: thread = 2 rows x 4 cols; W read from global (L1/L2 resident)
    const int tx = tid & 15, ty = tid >> 4;   // ty 0..15
    const int j0 = tx * 4;
    const int i0 = ty * 2;

    float acc[2][4];
    float4 b4 = *(const float4*)&bl[j0];
#pragma unroll
    for (int i = 0; i < 2; ++i) {
        acc[i][0] = b4.x; acc[i][1] = b4.y; acc[i][2] = b4.z; acc[i][3] = b4.w;
    }

    for (int k = 0; k < 64; k += 4) {
        float4 wl[4], wr[4];
#pragma unroll
        for (int kk = 0; kk < 4; ++kk) {
            wl[kk] = *(const float4*)&Wl[(k + kk) * D + j0];
            wr[kk] = *(const float4*)&Wr[(k + kk) * D + j0];
        }
#pragma unroll
        for (int i = 0; i < 2; ++i) {
            float4 m  = *(const float4*)&sM[i0 + i][k];
            float4 xv = *(const float4*)&sX[i0 + i][k];
            float mk[4] = {m.x, m.y, m.z, m.w};
            float xk[4] = {xv.x, xv.y, xv.z, xv.w};
#pragma unroll
            for (int kk = 0; kk < 4; ++kk) {
                acc[i][0] += mk[kk] * wl[kk].x + xk[kk] * wr[kk].x;
                acc[i][1] += mk[kk] * wl[kk].y + xk[kk] * wr[kk].y;
                acc[i][2] += mk[kk] * wl[kk].z + xk[kk] * wr[kk].z;
                acc[i][3] += mk[kk] * wl[kk].w + xk[kk] * wr[kk].w;
            }
        }
    }

#pragma unroll
    for (int i = 0; i < 2; ++i) {
        int n = row0 + i0 + i;
        if (n < N_NODES) {
            float o[4];
#pragma unroll
            for (int j = 0; j < 4; ++j)
                o[j] = relu ? fmaxf(acc[i][j], 0.f) : acc[i][j];
            if constexpr (__hip_internal::is_same<TOUT, unsigned short>::value) {
                ushort4 u;
                u.x = f2bf(o[0]); u.y = f2bf(o[1]); u.z = f2bf(o[2]); u.w = f2bf(o[3]);
                *(ushort4*)&out[(size_t)n * D + j0] = u;
            } else {
                float4 f;
                f.x = o[0]; f.y = o[1]; f.z = o[2]; f.w = o[3];
                *(float4*)&out[(size_t)n * D + j0] = f;
            }
        }
    }
}

extern "C" void kernel_launch(void* const* d_in, const int* in_sizes, int n_in,
                              void* d_out, int out_size, void* d_ws, size_t ws_size,
                              hipStream_t stream) {
    const float* x   = (const float*)d_in[0];
    const int*   ei  = (const int*)d_in[1];
    const float* Wl1 = (const float*)d_in[2];
    const float* b1  = (const float*)d_in[3];
    const float* Wr1 = (const float*)d_in[4];
    const float* Wl2 = (const float*)d_in[5];
    const float* b2  = (const float*)d_in[6];
    const float* Wr2 = (const float*)d_in[7];

    const int* src = ei;
    const int* dst = ei + N_EDGES;

    // ws layout (ints): hist[100000] | cursor[100000] | partials[128] | sorted_src[1250000] | h_bf16
    int* hist       = (int*)d_ws;
    int* cursor     = hist + N_NODES;
    int* partials   = cursor + N_NODES;
    int* sorted_src = partials + 128;
    unsigned short* h = (unsigned short*)(sorted_src + N_EDGES);   // [N, D] bf16
    float* out = (float*)d_out;
    // xb (bf16 x) lives in d_out: dead until layer 2 fully rewrites d_out from h.
    unsigned short* xb = (unsigned short*)d_out;

    const int edge_blocks = (N_EDGES + 255) / 256;
    const int node_blocks = (N_NODES + 255) / 256;
    const int dense_blocks = (N_NODES + 31) / 32;
    const int conv4 = N_NODES * D / 4;

    // x -> bf16 (into d_out scratch region)
    convert_kernel<<<(conv4 + 255) / 256, 256, 0, stream>>>((const float4*)x, (ushort4*)xb, conv4);

    // build CSR (dst-sorted srcs)
    zero_int_kernel<<<node_blocks, 256, 0, stream>>>(hist, N_NODES);
    hist_kernel<<<edge_blocks, 256, 0, stream>>>(dst, hist);
    scan_reduce_kernel<<<SCAN_NB, SCAN_TPB, 0, stream>>>(hist, partials);
    scan_partials_kernel<<<1, 128, 0, stream>>>(partials);
    scan_write_kernel<<<SCAN_NB, SCAN_TPB, 0, stream>>>(hist, partials, cursor);
    bucket_kernel<<<edge_blocks, 256, 0, stream>>>(src, dst, cursor, sorted_src);

    // layer 1: xb (bf16, in d_out) -> h (bf16, ws)
    fused_layer_kernel<unsigned short><<<dense_blocks, 256, 0, stream>>>(
        xb, cursor, hist, sorted_src, Wl1, b1, Wr1, h, /*relu=*/1);
    // layer 2: h (bf16) -> out (fp32, d_out) — overwrites xb entirely
    fused_layer_kernel<float><<<dense_blocks, 256, 0, stream>>>(
        h, cursor, hist, sorted_src, Wl2, b2, Wr2, out, /*relu=*/0);
}

// Round 5
// 419.434 us; speedup vs baseline: 2.7541x; 1.0216x over previous
//
#include <hip/hip_runtime.h>

#define N_NODES 100000
#define N_EDGES 1250000
#define D 64

#define SCAN_TPB 256
#define SCAN_ELEMS 1024
#define SCAN_NB ((N_NODES + SCAN_ELEMS - 1) / SCAN_ELEMS)   // 98

// ---- bf16 helpers (finite values only) ----
__device__ inline unsigned short f2bf(float f) {
    unsigned int u = __float_as_uint(f);
    unsigned int r = (u + 0x7fffu + ((u >> 16) & 1u)) >> 16;
    return (unsigned short)r;
}
__device__ inline float2 unpack_bf2(unsigned int u) {
    float2 f;
    f.x = __uint_as_float(u << 16);
    f.y = __uint_as_float(u & 0xffff0000u);
    return f;
}

// ---------------- x fp32 -> bf16, fused with hist zeroing ----------------
__global__ __launch_bounds__(256)
void convert_zero_kernel(const float4* __restrict__ xin, ushort4* __restrict__ xb,
                         int n4, int4* __restrict__ hist4, int nh4) {
    int i = blockIdx.x * 256 + threadIdx.x;
    if (i < n4) {
        float4 v = xin[i];
        ushort4 u;
        u.x = f2bf(v.x); u.y = f2bf(v.y); u.z = f2bf(v.z); u.w = f2bf(v.w);
        xb[i] = u;
    }
    if (i < nh4) hist4[i] = make_int4(0, 0, 0, 0);
}

// ---------------- degree histogram (4 edges/thread) ----------------
__global__ __launch_bounds__(256)
void hist_kernel(const int4* __restrict__ dst4, int* __restrict__ hist) {
    int i = blockIdx.x * 256 + threadIdx.x;
    if (i < N_EDGES / 4) {
        int4 d = dst4[i];
        atomicAdd(&hist[d.x], 1);
        atomicAdd(&hist[d.y], 1);
        atomicAdd(&hist[d.z], 1);
        atomicAdd(&hist[d.w], 1);
    }
}

// ---------------- scan step 1: per-block reduce ----------------
__global__ __launch_bounds__(SCAN_TPB)
void scan_reduce_kernel(const int* __restrict__ hist, int* __restrict__ partials) {
    __shared__ int sdata[SCAN_TPB];
    int t = threadIdx.x;
    int base = blockIdx.x * SCAN_ELEMS + t * 4;
    int s = 0;
#pragma unroll
    for (int k = 0; k < 4; ++k) {
        int i = base + k;
        if (i < N_NODES) s += hist[i];
    }
    sdata[t] = s;
    __syncthreads();
    for (int off = SCAN_TPB / 2; off > 0; off >>= 1) {
        if (t < off) sdata[t] += sdata[t + off];
        __syncthreads();
    }
    if (t == 0) partials[blockIdx.x] = sdata[0];
}

// ---------------- scan step 2: exclusive scan of partials (1 block) ----------------
__global__ __launch_bounds__(128)
void scan_partials_kernel(int* __restrict__ partials) {
    __shared__ int s[128];
    int t = threadIdx.x;
    int v = (t < SCAN_NB) ? partials[t] : 0;
    s[t] = v;
    __syncthreads();
    for (int off = 1; off < 128; off <<= 1) {
        int x = (t >= off) ? s[t - off] : 0;
        __syncthreads();
        s[t] += x;
        __syncthreads();
    }
    if (t < SCAN_NB) partials[t] = (t == 0) ? 0 : s[t - 1];
}

// ---------------- scan step 3: write exclusive prefix -> cursor ----------------
__global__ __launch_bounds__(SCAN_TPB)
void scan_write_kernel(const int* __restrict__ hist, const int* __restrict__ partials,
                       int* __restrict__ cursor) {
    __shared__ int sdata[SCAN_TPB];
    int t = threadIdx.x;
    int base = blockIdx.x * SCAN_ELEMS + t * 4;
    int h[4];
    int tot = 0;
#pragma unroll
    for (int k = 0; k < 4; ++k) {
        int i = base + k;
        h[k] = (i < N_NODES) ? hist[i] : 0;
        tot += h[k];
    }
    sdata[t] = tot;
    __syncthreads();
    for (int off = 1; off < SCAN_TPB; off <<= 1) {
        int x = (t >= off) ? sdata[t - off] : 0;
        __syncthreads();
        sdata[t] += x;
        __syncthreads();
    }
    int run = partials[blockIdx.x] + sdata[t] - tot;   // exclusive thread prefix
#pragma unroll
    for (int k = 0; k < 4; ++k) {
        int i = base + k;
        if (i < N_NODES) { cursor[i] = run; run += h[k]; }
    }
}

// ---------------- bucket: counting-sort srcs by dst (4 edges/thread) ----------------
__global__ __launch_bounds__(256)
void bucket_kernel(const int4* __restrict__ src4, const int4* __restrict__ dst4,
                   int* __restrict__ cursor, int* __restrict__ sorted_src) {
    int i = blockIdx.x * 256 + threadIdx.x;
    if (i < N_EDGES / 4) {
        int4 s = src4[i];
        int4 d = dst4[i];
        sorted_src[atomicAdd(&cursor[d.x], 1)] = s.x;
        sorted_src[atomicAdd(&cursor[d.y], 1)] = s.y;
        sorted_src[atomicAdd(&cursor[d.z], 1)] = s.z;
        sorted_src[atomicAdd(&cursor[d.w], 1)] = s.w;
    }
}

// ---------------- fused layer: gather-mean + (mean@Wl + b + x@Wr) ----------------
// bf16 input. Edge-paired gather: uint (2 bf16) per lane, 32 lanes/row,
// lanes 0-31 = edge 2j, lanes 32-63 = edge 2j+1; combine via shfl_xor(32).
// 17.4 KB LDS, 8 blocks/CU.
template <typename TOUT>
__global__ __launch_bounds__(256, 8)
void fused_layer_kernel(const unsigned short* __restrict__ xin,   // bf16 [N,D]
                        const int* __restrict__ cursor_end,
                        const int* __restrict__ deg,
                        const int* __restrict__ sorted_src,
                        const float* __restrict__ Wl,
                        const float* __restrict__ bl,
                        const float* __restrict__ Wr,
                        TOUT* __restrict__ out,
                        int relu) {
    __shared__ float sM[32][68];
    __shared__ float sX[32][68];

    const unsigned int* __restrict__ xin32 = (const unsigned int*)xin;

    const int tid = threadIdx.x;
    const int row0 = blockIdx.x * 32;

    const int wave = tid >> 6;
    const int lane = tid & 63;
    const int half = lane >> 5;          // 0: even edges, 1: odd edges
    const int l32 = lane & 31;
    const int fl = l32 * 2;              // feature pair base

    for (int r = wave; r < 32; r += 4) {
        int n = row0 + r;
        float ax = 0.f, ay = 0.f;
        float2 xv = make_float2(0.f, 0.f);
        int dg = 0;
        if (n < N_NODES) {
            dg = deg[n];
            int st = cursor_end[n] - dg;
            xv = unpack_bf2(xin32[(size_t)n * 32 + l32]);
            for (int base = 0; base < dg; base += 64) {
                int m = dg - base; if (m > 64) m = 64;
                int idx = 0;
                if (lane < m) idx = sorted_src[st + base + lane];
                int pairs = m >> 1;
                float a0x = 0.f, a0y = 0.f, a1x = 0.f, a1y = 0.f;
                float a2x = 0.f, a2y = 0.f, a3x = 0.f, a3y = 0.f;
                int j = 0;
                for (; j + 4 <= pairs; j += 4) {
#pragma unroll
                    for (int q = 0; q < 4; ++q) {
                        int e0 = __builtin_amdgcn_readlane(idx, 2 * (j + q));
                        int e1 = __builtin_amdgcn_readlane(idx, 2 * (j + q) + 1);
                        int s = half ? e1 : e0;
                        float2 f = unpack_bf2(xin32[(size_t)s * 32 + l32]);
                        if (q == 0) { a0x += f.x; a0y += f.y; }
                        else if (q == 1) { a1x += f.x; a1y += f.y; }
                        else if (q == 2) { a2x += f.x; a2y += f.y; }
                        else { a3x += f.x; a3y += f.y; }
                    }
                }
                for (; j < pairs; ++j) {
                    int e0 = __builtin_amdgcn_readlane(idx, 2 * j);
                    int e1 = __builtin_amdgcn_readlane(idx, 2 * j + 1);
                    int s = half ? e1 : e0;
                    float2 f = unpack_bf2(xin32[(size_t)s * 32 + l32]);
                    a0x += f.x; a0y += f.y;
                }
                if (m & 1) {
                    int s = __builtin_amdgcn_readlane(idx, m - 1);
                    if (half == 0) {
                        float2 f = unpack_bf2(xin32[(size_t)s * 32 + l32]);
                        a1x += f.x; a1y += f.y;
                    }
                }
                ax += (a0x + a1x) + (a2x + a3x);
                ay += (a0y + a1y) + (a2y + a3y);
            }
            // combine even-edge half with odd-edge half
            ax += __shfl_xor(ax, 32);
            ay += __shfl_xor(ay, 32);
        }
        float inv = 1.0f / (float)(dg > 0 ? dg : 1);
        if (half == 0) {
            *(float2*)&sM[r][fl] = make_float2(ax * inv, ay * inv);
            *(float2*)&sX[r][fl] = xv;
        }
    }
    __syncthreads();

    // GEMM phase: thread = 2 rows x 4 cols; W read from global (L1/L2 resident)
    const int tx = tid & 15, ty = tid >> 4;   // ty 0..15
    const int j0 = tx * 4;
    const int i0 = ty * 2;

    float acc[2][4];
    float4 b4 = *(const float4*)&bl[j0];
#pragma unroll
    for (int i = 0; i < 2; ++i) {
        acc[i][0] = b4.x; acc[i][1] = b4.y; acc[i][2] = b4.z; acc[i][3] = b4.w;
    }

    for (int k = 0; k < 64; k += 4) {
        float4 wl[4], wr[4];
#pragma unroll
        for (int kk = 0; kk < 4; ++kk) {
            wl[kk] = *(const float4*)&Wl[(k + kk) * D + j0];
            wr[kk] = *(const float4*)&Wr[(k + kk) * D + j0];
        }
#pragma unroll
        for (int i = 0; i < 2; ++i) {
            float4 m  = *(const float4*)&sM[i0 + i][k];
            float4 xv = *(const float4*)&sX[i0 + i][k];
            float mk[4] = {m.x, m.y, m.z, m.w};
            float xk[4] = {xv.x, xv.y, xv.z, xv.w};
#pragma unroll
            for (int kk = 0; kk < 4; ++kk) {
                acc[i][0] += mk[kk] * wl[kk].x + xk[kk] * wr[kk].x;
                acc[i][1] += mk[kk] * wl[kk].y + xk[kk] * wr[kk].y;
                acc[i][2] += mk[kk] * wl[kk].z + xk[kk] * wr[kk].z;
                acc[i][3] += mk[kk] * wl[kk].w + xk[kk] * wr[kk].w;
            }
        }
    }

#pragma unroll
    for (int i = 0; i < 2; ++i) {
        int n = row0 + i0 + i;
        if (n < N_NODES) {
            float o[4];
#pragma unroll
            for (int j = 0; j < 4; ++j)
                o[j] = relu ? fmaxf(acc[i][j], 0.f) : acc[i][j];
            if constexpr (__hip_internal::is_same<TOUT, unsigned short>::value) {
                ushort4 u;
                u.x = f2bf(o[0]); u.y = f2bf(o[1]); u.z = f2bf(o[2]); u.w = f2bf(o[3]);
                *(ushort4*)&out[(size_t)n * D + j0] = u;
            } else {
                float4 f;
                f.x = o[0]; f.y = o[1]; f.z = o[2]; f.w = o[3];
                *(float4*)&out[(size_t)n * D + j0] = f;
            }
        }
    }
}

extern "C" void kernel_launch(void* const* d_in, const int* in_sizes, int n_in,
                              void* d_out, int out_size, void* d_ws, size_t ws_size,
                              hipStream_t stream) {
    const float* x   = (const float*)d_in[0];
    const int*   ei  = (const int*)d_in[1];
    const float* Wl1 = (const float*)d_in[2];
    const float* b1  = (const float*)d_in[3];
    const float* Wr1 = (const float*)d_in[4];
    const float* Wl2 = (const float*)d_in[5];
    const float* b2  = (const float*)d_in[6];
    const float* Wr2 = (const float*)d_in[7];

    const int* src = ei;
    const int* dst = ei + N_EDGES;

    // ws layout (ints): hist[100000] | cursor[100000] | partials[128] | sorted_src[1250000] | h_bf16
    int* hist       = (int*)d_ws;
    int* cursor     = hist + N_NODES;
    int* partials   = cursor + N_NODES;
    int* sorted_src = partials + 128;
    unsigned short* h = (unsigned short*)(sorted_src + N_EDGES);   // [N, D] bf16
    float* out = (float*)d_out;
    // xb (bf16 x) lives in d_out: dead until layer 2 fully rewrites d_out from h.
    unsigned short* xb = (unsigned short*)d_out;

    const int edge4_blocks = (N_EDGES / 4 + 255) / 256;
    const int dense_blocks = (N_NODES + 31) / 32;
    const int conv4 = N_NODES * D / 4;

    // x -> bf16 (into d_out scratch) + zero hist, one kernel
    convert_zero_kernel<<<(conv4 + 255) / 256, 256, 0, stream>>>(
        (const float4*)x, (ushort4*)xb, conv4, (int4*)hist, N_NODES / 4);

    // build CSR (dst-sorted srcs)
    hist_kernel<<<edge4_blocks, 256, 0, stream>>>((const int4*)dst, hist);
    scan_reduce_kernel<<<SCAN_NB, SCAN_TPB, 0, stream>>>(hist, partials);
    scan_partials_kernel<<<1, 128, 0, stream>>>(partials);
    scan_write_kernel<<<SCAN_NB, SCAN_TPB, 0, stream>>>(hist, partials, cursor);
    bucket_kernel<<<edge4_blocks, 256, 0, stream>>>((const int4*)src, (const int4*)dst,
                                                    cursor, sorted_src);

    // layer 1: xb (bf16, in d_out) -> h (bf16, ws)
    fused_layer_kernel<unsigned short><<<dense_blocks, 256, 0, stream>>>(
        xb, cursor, hist, sorted_src, Wl1, b1, Wr1, h, /*relu=*/1);
    // layer 2: h (bf16) -> out (fp32, d_out) — overwrites xb entirely
    fused_layer_kernel<float><<<dense_blocks, 256, 0, stream>>>(
        h, cursor, hist, sorted_src, Wl2, b2, Wr2, out, /*relu=*/0);
}